// Round 1
// baseline (6207.187 us; speedup 1.0000x reference)
//
#include <hip/hip_runtime.h>

constexpr int B_ = 4, S_ = 2048, D_ = 1024, H_ = 16, DK_ = 64;

// ---------------------------------------------------------------------------
// GEMM (NT): C[m,n] = sum_k A[m,k] * W[n,k].  A:[M,K] row-major, W:[N,K] row-major.
// MODE 0: scatter into [B,H,S,DK] head-split layout.  MODE 1: plain [M,N].
// 128x128 tile, BK=16, 256 threads, 8x8 per thread.
// ---------------------------------------------------------------------------
template<int MODE>
__global__ __launch_bounds__(256)
void gemm_nt(const float* __restrict__ A, const float* __restrict__ W,
             float* __restrict__ out)
{
    constexpr int K = D_;
    __shared__ __align__(16) float As[16][132];
    __shared__ __align__(16) float Ws[16][132];

    const int m0 = blockIdx.y * 128;
    const int n0 = blockIdx.x * 128;
    const int t  = threadIdx.x;
    const int lr = t >> 1;          // 0..127
    const int lk = (t & 1) << 3;    // 0 or 8
    const int tx = t & 15;
    const int ty = t >> 4;

    float acc[8][8];
    #pragma unroll
    for (int i = 0; i < 8; ++i)
        #pragma unroll
        for (int j = 0; j < 8; ++j) acc[i][j] = 0.f;

    const float* Ap = A + (size_t)(m0 + lr) * K + lk;
    const float* Wp = W + (size_t)(n0 + lr) * K + lk;

    for (int k0 = 0; k0 < K; k0 += 16) {
        const float4 a0 = *(const float4*)(Ap + k0);
        const float4 a1 = *(const float4*)(Ap + k0 + 4);
        const float4 w0 = *(const float4*)(Wp + k0);
        const float4 w1 = *(const float4*)(Wp + k0 + 4);
        __syncthreads();   // previous iteration's LDS reads complete
        As[lk+0][lr]=a0.x; As[lk+1][lr]=a0.y; As[lk+2][lr]=a0.z; As[lk+3][lr]=a0.w;
        As[lk+4][lr]=a1.x; As[lk+5][lr]=a1.y; As[lk+6][lr]=a1.z; As[lk+7][lr]=a1.w;
        Ws[lk+0][lr]=w0.x; Ws[lk+1][lr]=w0.y; Ws[lk+2][lr]=w0.z; Ws[lk+3][lr]=w0.w;
        Ws[lk+4][lr]=w1.x; Ws[lk+5][lr]=w1.y; Ws[lk+6][lr]=w1.z; Ws[lk+7][lr]=w1.w;
        __syncthreads();
        #pragma unroll
        for (int k = 0; k < 16; ++k) {
            const float4 av0 = *(const float4*)&As[k][ty*8];
            const float4 av1 = *(const float4*)&As[k][ty*8+4];
            const float4 bv0 = *(const float4*)&Ws[k][tx*8];
            const float4 bv1 = *(const float4*)&Ws[k][tx*8+4];
            const float am[8] = {av0.x,av0.y,av0.z,av0.w,av1.x,av1.y,av1.z,av1.w};
            const float bn[8] = {bv0.x,bv0.y,bv0.z,bv0.w,bv1.x,bv1.y,bv1.z,bv1.w};
            #pragma unroll
            for (int i = 0; i < 8; ++i)
                #pragma unroll
                for (int j = 0; j < 8; ++j)
                    acc[i][j] = fmaf(am[i], bn[j], acc[i][j]);
        }
    }

    #pragma unroll
    for (int i = 0; i < 8; ++i) {
        const int m = m0 + ty*8 + i;
        #pragma unroll
        for (int jj = 0; jj < 8; jj += 4) {
            const int n = n0 + tx*8 + jj;
            const float4 v = make_float4(acc[i][jj], acc[i][jj+1],
                                         acc[i][jj+2], acc[i][jj+3]);
            if (MODE == 0) {
                const int b = m >> 11, s = m & (S_ - 1);
                const int h = n >> 6,  dk = n & (DK_ - 1);
                *(float4*)&out[(((size_t)(b*H_ + h))*S_ + s)*DK_ + dk] = v;
            } else {
                *(float4*)&out[(size_t)m*D_ + n] = v;
            }
        }
    }
}

// ---------------------------------------------------------------------------
// Fused causal attention. One WG per (q-tile of 64 rows, head, batch).
// Two-pass online softmax: pass 1 computes per-row (m,l) streaming over K
// tiles; pass 2 recomputes scores, writes normalized attn, accumulates P*V.
// Thread layout: tx = col group (4 cols), ty = row group (4 rows).
// ---------------------------------------------------------------------------
__global__ __launch_bounds__(256)
void attn_fused(const float* __restrict__ Qp, const float* __restrict__ Kp,
                const float* __restrict__ Vp, float* __restrict__ attn,
                float* __restrict__ ctx)
{
    __shared__ __align__(16) float Qs[64][68];   // Q^T: [d][m]
    __shared__ __align__(16) float Ks[64][68];   // K^T: [d][n]  (pass2: reused as P[c][m])
    __shared__ __align__(16) float Vs[64][68];   // V:   [c][dv]

    const int qt = blockIdx.x, h = blockIdx.y, b = blockIdx.z;
    const int bh = b*H_ + h;
    const int q0 = qt * 64;
    const float* Qb = Qp + (size_t)bh * S_ * DK_;
    const float* Kb = Kp + (size_t)bh * S_ * DK_;
    const float* Vb = Vp + (size_t)bh * S_ * DK_;
    float* attn_b = attn + (size_t)bh * S_ * S_;

    const int t  = threadIdx.x;
    const int lr = t >> 2;          // 0..63
    const int lc = (t & 3) << 4;    // 0,16,32,48
    const int tx = t & 15;
    const int ty = t >> 4;

    // Q tile -> LDS transposed
    #pragma unroll
    for (int i = 0; i < 16; i += 4) {
        const float4 v = *(const float4*)&Qb[(size_t)(q0 + lr)*DK_ + lc + i];
        Qs[lc+i+0][lr]=v.x; Qs[lc+i+1][lr]=v.y; Qs[lc+i+2][lr]=v.z; Qs[lc+i+3][lr]=v.w;
    }

    float mreg[4], lreg[4];
    #pragma unroll
    for (int i = 0; i < 4; ++i) { mreg[i] = -1e30f; lreg[i] = 0.f; }

    // ---------------- pass 1: running (m, l) ----------------
    for (int kt = 0; kt <= qt; ++kt) {
        const int k0 = kt * 64;
        __syncthreads();            // prior compute done before Ks overwrite
        #pragma unroll
        for (int i = 0; i < 16; i += 4) {
            const float4 v = *(const float4*)&Kb[(size_t)(k0 + lr)*DK_ + lc + i];
            Ks[lc+i+0][lr]=v.x; Ks[lc+i+1][lr]=v.y; Ks[lc+i+2][lr]=v.z; Ks[lc+i+3][lr]=v.w;
        }
        __syncthreads();

        float sv[4][4];
        #pragma unroll
        for (int i = 0; i < 4; ++i)
            #pragma unroll
            for (int j = 0; j < 4; ++j) sv[i][j] = 0.f;
        #pragma unroll
        for (int d = 0; d < 64; ++d) {
            const float4 a  = *(const float4*)&Qs[d][ty*4];
            const float4 bv = *(const float4*)&Ks[d][tx*4];
            const float am[4] = {a.x,a.y,a.z,a.w};
            const float bn[4] = {bv.x,bv.y,bv.z,bv.w};
            #pragma unroll
            for (int i = 0; i < 4; ++i)
                #pragma unroll
                for (int j = 0; j < 4; ++j)
                    sv[i][j] = fmaf(am[i], bn[j], sv[i][j]);
        }
        #pragma unroll
        for (int i = 0; i < 4; ++i) {
            const int q = q0 + ty*4 + i;
            float rm = -1e30f;
            #pragma unroll
            for (int j = 0; j < 4; ++j) {
                sv[i][j] *= 0.125f;                       // 1/sqrt(64)
                if (k0 + tx*4 + j > q) sv[i][j] = -1e30f; // causal mask
                rm = fmaxf(rm, sv[i][j]);
            }
            const float nm = fmaxf(mreg[i], rm);
            float add = 0.f;
            #pragma unroll
            for (int j = 0; j < 4; ++j) add += __expf(sv[i][j] - nm);
            lreg[i] = lreg[i] * __expf(mreg[i] - nm) + add;
            mreg[i] = nm;
        }
    }

    // merge (m,l) across the 16 lanes sharing each row
    float linv[4];
    #pragma unroll
    for (int i = 0; i < 4; ++i) {
        #pragma unroll
        for (int off = 1; off < 16; off <<= 1) {
            const float om = __shfl_xor(mreg[i], off, 16);
            const float ol = __shfl_xor(lreg[i], off, 16);
            const float nm = fmaxf(mreg[i], om);
            lreg[i] = lreg[i] * __expf(mreg[i] - nm) + ol * __expf(om - nm);
            mreg[i] = nm;
        }
        linv[i] = 1.0f / lreg[i];
    }

    // ---------------- pass 2: attn write + P*V ----------------
    float ctxacc[4][4];
    #pragma unroll
    for (int i = 0; i < 4; ++i)
        #pragma unroll
        for (int j = 0; j < 4; ++j) ctxacc[i][j] = 0.f;

    for (int kt = 0; kt <= qt; ++kt) {
        const int k0 = kt * 64;
        __syncthreads();            // prior PV reads done before K/V overwrite
        #pragma unroll
        for (int i = 0; i < 16; i += 4) {
            const float4 v = *(const float4*)&Kb[(size_t)(k0 + lr)*DK_ + lc + i];
            Ks[lc+i+0][lr]=v.x; Ks[lc+i+1][lr]=v.y; Ks[lc+i+2][lr]=v.z; Ks[lc+i+3][lr]=v.w;
            const float4 w = *(const float4*)&Vb[(size_t)(k0 + lr)*DK_ + lc + i];
            *(float4*)&Vs[lr][lc+i] = w;
        }
        __syncthreads();

        float sv[4][4];
        #pragma unroll
        for (int i = 0; i < 4; ++i)
            #pragma unroll
            for (int j = 0; j < 4; ++j) sv[i][j] = 0.f;
        #pragma unroll
        for (int d = 0; d < 64; ++d) {
            const float4 a  = *(const float4*)&Qs[d][ty*4];
            const float4 bv = *(const float4*)&Ks[d][tx*4];
            const float am[4] = {a.x,a.y,a.z,a.w};
            const float bn[4] = {bv.x,bv.y,bv.z,bv.w};
            #pragma unroll
            for (int i = 0; i < 4; ++i)
                #pragma unroll
                for (int j = 0; j < 4; ++j)
                    sv[i][j] = fmaf(am[i], bn[j], sv[i][j]);
        }

        float p[4][4];
        #pragma unroll
        for (int i = 0; i < 4; ++i) {
            const int q = q0 + ty*4 + i;
            #pragma unroll
            for (int j = 0; j < 4; ++j) {
                const int c = k0 + tx*4 + j;
                p[i][j] = (c <= q) ? __expf(sv[i][j]*0.125f - mreg[i]) * linv[i] : 0.f;
            }
            *(float4*)&attn_b[(size_t)q*S_ + k0 + tx*4] =
                make_float4(p[i][0], p[i][1], p[i][2], p[i][3]);
        }

        __syncthreads();            // all score reads of Ks done
        #pragma unroll
        for (int i = 0; i < 4; ++i)
            #pragma unroll
            for (int j = 0; j < 4; ++j)
                Ks[tx*4+j][ty*4+i] = p[i][j];   // reuse Ks as P[c][m]
        __syncthreads();

        #pragma unroll
        for (int c = 0; c < 64; ++c) {
            const float4 a  = *(const float4*)&Ks[c][ty*4];  // P[c][rows]
            const float4 bv = *(const float4*)&Vs[c][tx*4];  // V[c][dv]
            const float am[4] = {a.x,a.y,a.z,a.w};
            const float bn[4] = {bv.x,bv.y,bv.z,bv.w};
            #pragma unroll
            for (int i = 0; i < 4; ++i)
                #pragma unroll
                for (int j = 0; j < 4; ++j)
                    ctxacc[i][j] = fmaf(am[i], bn[j], ctxacc[i][j]);
        }
    }

    // zero-fill masked upper region of attn rows
    {
        const int r  = t >> 2;
        const int c4 = (t & 3) << 2;
        const float4 z = make_float4(0.f, 0.f, 0.f, 0.f);
        for (int col = (qt + 1)*64 + c4; col < S_; col += 16)
            *(float4*)&attn_b[(size_t)(q0 + r)*S_ + col] = z;
    }

    // write context into [B,S,D] (d = h*64 + dv)
    #pragma unroll
    for (int i = 0; i < 4; ++i) {
        const int q = q0 + ty*4 + i;
        *(float4*)&ctx[((size_t)b*S_ + q)*D_ + h*DK_ + tx*4] =
            make_float4(ctxacc[i][0], ctxacc[i][1], ctxacc[i][2], ctxacc[i][3]);
    }
}

// ---------------------------------------------------------------------------
extern "C" void kernel_launch(void* const* d_in, const int* in_sizes, int n_in,
                              void* d_out, int out_size, void* d_ws, size_t ws_size,
                              hipStream_t stream)
{
    const float* query = (const float*)d_in[0];
    const float* key   = (const float*)d_in[1];
    const float* value = (const float*)d_in[2];
    // d_in[3] = causal mask (tril), structure known -> unused
    const float* W_q = (const float*)d_in[4];
    const float* W_k = (const float*)d_in[5];
    const float* W_v = (const float*)d_in[6];
    const float* W_o = (const float*)d_in[7];

    float* out  = (float*)d_out;                       // [B,S,D]
    float* attn = out + (size_t)B_ * S_ * D_;          // [B,H,S,S]

    float* ws  = (float*)d_ws;                         // needs 4 x 32 MiB
    float* Qp  = ws;
    float* Kp  = Qp + (size_t)B_ * S_ * D_;
    float* Vp  = Kp + (size_t)B_ * S_ * D_;
    float* ctx = Vp + (size_t)B_ * S_ * D_;

    const dim3 gg(D_ / 128, (B_ * S_) / 128);          // (8, 64)
    gemm_nt<0><<<gg, 256, 0, stream>>>(query, W_q, Qp);
    gemm_nt<0><<<gg, 256, 0, stream>>>(key,   W_k, Kp);
    gemm_nt<0><<<gg, 256, 0, stream>>>(value, W_v, Vp);

    attn_fused<<<dim3(S_/64, H_, B_), 256, 0, stream>>>(Qp, Kp, Vp, attn, ctx);

    gemm_nt<1><<<gg, 256, 0, stream>>>(ctx, W_o, out);
}